// Round 14
// baseline (107.503 us; speedup 1.0000x reference)
//
#include <hip/hip_runtime.h>
#include <stdint.h>

#define BATCH 16
#define SEQ   4096
#define DIM   256
#define HW    64
#define NSTEP 10
#define DT    0.3f

typedef __attribute__((ext_vector_type(8))) short short8;   // 8 bf16 in 4 VGPRs
typedef __attribute__((ext_vector_type(4))) float f32x4;
typedef __attribute__((ext_vector_type(2))) float f32x2;

// ---------------------------------------------------------------------------
// Packed-f32 VOP3P helpers (throughput-neutral vs scalar per R8; kept for
// density). One SGPR source max per instruction.
// ---------------------------------------------------------------------------
__device__ __forceinline__ f32x2 pk_add(f32x2 a, f32x2 b) {
  f32x2 d; asm("v_pk_add_f32 %0, %1, %2" : "=v"(d) : "v"(a), "v"(b)); return d;
}
__device__ __forceinline__ f32x2 pk_mul(f32x2 a, f32x2 b) {
  f32x2 d; asm("v_pk_mul_f32 %0, %1, %2" : "=v"(d) : "v"(a), "v"(b)); return d;
}
// d = a*b + ks (addend in SGPR pair)
__device__ __forceinline__ f32x2 pk_fma_addk(f32x2 a, f32x2 b, f32x2 ks) {
  f32x2 d; asm("v_pk_fma_f32 %0, %1, %2, %3" : "=v"(d) : "v"(a), "v"(b), "s"(ks)); return d;
}
// d = a*ks + c (multiplier in SGPR pair)
__device__ __forceinline__ f32x2 pk_fma_s1(f32x2 a, f32x2 ks, f32x2 c) {
  f32x2 d; asm("v_pk_fma_f32 %0, %1, %2, %3" : "=v"(d) : "v"(a), "s"(ks), "v"(c)); return d;
}

// DPP lane shifts. With 16 lanes across, DPP 16-lane row boundaries coincide
// with plane edges: bound_ctrl zeroes the halo at lx==0 / lx==15 FOR FREE.
__device__ __forceinline__ float dpp_from_left(float x) {   // lane i <- lane i-1
  return __int_as_float(__builtin_amdgcn_update_dpp(
      0, __float_as_int(x), 0x111 /*row_shr:1*/, 0xF, 0xF, true));
}
__device__ __forceinline__ float dpp_from_right(float x) {  // lane i <- lane i+1
  return __int_as_float(__builtin_amdgcn_update_dpp(
      0, __float_as_int(x), 0x101 /*row_shl:1*/, 0xF, 0xF, true));
}

// round-to-nearest-even fp32 -> bf16 (bits in high 16)
__device__ __forceinline__ float bfhi(float a) {
  uint32_t u = __float_as_uint(a);
  u += 0x7FFFu + ((u >> 16) & 1u);
  return __uint_as_float(u & 0xFFFF0000u);
}
__device__ __forceinline__ uint32_t pack2(float a, float b) {
  uint32_t ua = __float_as_uint(a), ub = __float_as_uint(b);
  ua += 0x7FFFu + ((ua >> 16) & 1u);
  ub += 0x7FFFu + ((ub >> 16) & 1u);
  return (ua >> 16) | (ub & 0xFFFF0000u);
}

// ---------------------------------------------------------------------------
// GEMM: proj[(b*DIM+e)*SEQ + s] = sum_d x[b,s,d]*W[e,d] + bias[e]
// bf16x3 emulated-fp32 MFMA (unchanged; proven R3..R13).
// ---------------------------------------------------------------------------
__global__ __launch_bounds__(256) void gemm_proj_mfma(
    const float* __restrict__ x, const float* __restrict__ W,
    const float* __restrict__ bias, float* __restrict__ proj) {
  const int eTile = blockIdx.x * 128;
  const int sTile = blockIdx.y * 128;
  const int b     = blockIdx.z;
  const int t     = threadIdx.x;
  const int lane  = t & 63;
  const int wid   = t >> 6;
  const int wr    = wid >> 1;
  const int wc    = wid & 1;

  __shared__ char lds[4 * 128 * 80];
  char* Whs = lds;
  char* Wls = lds + 10240;
  char* Xhs = lds + 20480;
  char* Xls = lds + 30720;

  const float* xb = x + (size_t)b * SEQ * DIM;

  f32x4 acc[4][4] = {};
  float4 regW[4], regX[4];

#define ISSUE_LOADS(KT)                                                        \
  {                                                                            \
    _Pragma("unroll")                                                          \
    for (int r = 0; r < 4; r++) {                                              \
      int ci = t + 256 * r;                                                    \
      int row = ci >> 3, q = ci & 7;                                           \
      regW[r] = *(const float4*)(W  + (size_t)(eTile + row) * DIM + (KT) + q * 4); \
      regX[r] = *(const float4*)(xb + (size_t)(sTile + row) * DIM + (KT) + q * 4); \
    }                                                                          \
  }

  ISSUE_LOADS(0);

  for (int kt = 0; kt < DIM; kt += 32) {
    __syncthreads();
#pragma unroll
    for (int r = 0; r < 4; r++) {
      int ci = t + 256 * r;
      int row = ci >> 3, q = ci & 7;
      float4 v = regW[r];
      uint2 hi, lo;
      hi.x = pack2(v.x, v.y); hi.y = pack2(v.z, v.w);
      lo.x = pack2(v.x - bfhi(v.x), v.y - bfhi(v.y));
      lo.y = pack2(v.z - bfhi(v.z), v.w - bfhi(v.w));
      *(uint2*)(Whs + row * 80 + q * 8) = hi;
      *(uint2*)(Wls + row * 80 + q * 8) = lo;
      v = regX[r];
      hi.x = pack2(v.x, v.y); hi.y = pack2(v.z, v.w);
      lo.x = pack2(v.x - bfhi(v.x), v.y - bfhi(v.y));
      lo.y = pack2(v.z - bfhi(v.z), v.w - bfhi(v.w));
      *(uint2*)(Xhs + row * 80 + q * 8) = hi;
      *(uint2*)(Xls + row * 80 + q * 8) = lo;
    }
    __syncthreads();

    if (kt + 32 < DIM) ISSUE_LOADS(kt + 32);

    const int c16 = (lane >> 4) * 16;
    const int rlo = lane & 15;
    short8 bh[4], bl[4];
#pragma unroll
    for (int j = 0; j < 4; j++) {
      int rowX = wc * 64 + j * 16 + rlo;
      bh[j] = *(const short8*)(Xhs + rowX * 80 + c16);
      bl[j] = *(const short8*)(Xls + rowX * 80 + c16);
    }
#pragma unroll
    for (int i = 0; i < 4; i++) {
      int rowW = wr * 64 + i * 16 + rlo;
      short8 ah = *(const short8*)(Whs + rowW * 80 + c16);
      short8 al = *(const short8*)(Wls + rowW * 80 + c16);
#pragma unroll
      for (int j = 0; j < 4; j++) {
        acc[i][j] = __builtin_amdgcn_mfma_f32_16x16x32_bf16(ah, bh[j], acc[i][j], 0, 0, 0);
        acc[i][j] = __builtin_amdgcn_mfma_f32_16x16x32_bf16(ah, bl[j], acc[i][j], 0, 0, 0);
        acc[i][j] = __builtin_amdgcn_mfma_f32_16x16x32_bf16(al, bh[j], acc[i][j], 0, 0, 0);
      }
    }
  }
#undef ISSUE_LOADS

#pragma unroll
  for (int i = 0; i < 4; i++) {
    int e0 = eTile + wr * 64 + i * 16 + (lane >> 4) * 4;
#pragma unroll
    for (int reg = 0; reg < 4; reg++) {
      int e = e0 + reg;
      float bb = bias[e];
      float* orow = proj + ((size_t)(b * DIM + e)) * SEQ + sTile + wc * 64;
#pragma unroll
      for (int j = 0; j < 4; j++)
        orow[j * 16 + (lane & 15)] = acc[i][j][reg] + bb;
    }
  }
}

// ---------------------------------------------------------------------------
// Evolve: ONE wave per plane (no barriers, no LDS, no partner exchange).
// Lane = 16 rows x 4 cols (lx = lane&15 col-block, ly = lane>>4 row-block of
// 16 rows); u[16][2] f32x2 = 64 VGPR state. R13's measured 1365 cyc/wave-step
// vs ~800 counted -> ~500 cyc/wave-step of per-wave overhead (bpermute waits,
// barrier, LDS): this layout amortizes halo overhead over 2x cells and
// deletes barrier+LDS entirely. The 8 halo shfls are prefetched at step top
// and consumed 14+ rows later -> latency hidden. Row-compute identical to
// R13 (DPP side halos w/ free edge zeroing, Pade[5/4]+Ac-fold, shared rcp).
// 4096 waves = exactly 4/SIMD, all resident at __launch_bounds__(256,4)
// (128-VGPR budget; est. need ~100 -> no spills).
// ---------------------------------------------------------------------------
__global__ __launch_bounds__(256, 4) void evolve_kernel(
    const float* __restrict__ proj, const float* __restrict__ dcoef,
    float* __restrict__ out) {
  const int tid   = threadIdx.x;
  const int wid   = tid >> 6;
  const int lane  = tid & 63;
  const int plane = blockIdx.x * 4 + wid;  // = b*DIM + e
  const int lx = lane & 15;                // col block (4 cols)
  const int ly = lane >> 4;                // row block (16 rows)

  const float D   = dcoef[0];
  const float DDf = DT * D;
  const float Acf = 1.f - DT - 4.f * DDf;
  const float DDu = __uint_as_float(__builtin_amdgcn_readfirstlane(__float_as_uint(DDf)));
  const float Acu = __uint_as_float(__builtin_amdgcn_readfirstlane(__float_as_uint(Acf)));
  // Pade[5/4] fold: P(y) = (DT + 6*Ac)*y + 15*(DT + Ac);  Dn(y) = 6y + 15
  const float PAf = DT + 6.f * Acu;
  const float P0f = 15.f * (DT + Acu);
  const float P0u = __uint_as_float(__builtin_amdgcn_readfirstlane(__float_as_uint(P0f)));
  const f32x2 kDD  = {DDu, DDu};           // SGPR pair
  const f32x2 kP0  = {P0u, P0u};           // SGPR pair
  const f32x2 k15  = {15.f, 15.f};         // SGPR pair
  const f32x2 kPAv = {PAf, PAf};           // VGPR pair (multiplier slot)
  const f32x2 k6v  = {6.f, 6.f};           // VGPR pair

  const float* p = proj + (size_t)plane * (HW * HW)
                 + (size_t)(ly * 16) * HW + lx * 4;

  // u[r][q]: r = 0..15 rows, q = 0..1 col-pairs (4 cols/lane)
  f32x2 u[16][2];
#pragma unroll
  for (int r = 0; r < 16; r++) {
    float4 v = *(const float4*)(p + r * HW);
    u[r][0] = f32x2{v.x, v.y};
    u[r][1] = f32x2{v.z, v.w};
  }

  // 4 cells (2 pairs), shared reciprocal: z = sv*P(y)/Dn(y) + DD*s4
  auto pair2 = [&](f32x2 svA, f32x2 svB, f32x2 s4A, f32x2 s4B,
                   f32x2& zA, f32x2& zB) {
    f32x2 yA = pk_mul(svA, svA), yB = pk_mul(svB, svB);
    f32x2 tA = pk_fma_addk(yA, kPAv, kP0);
    f32x2 tB = pk_fma_addk(yB, kPAv, kP0);
    f32x2 nA = pk_mul(svA, tA);
    f32x2 nB = pk_mul(svB, tB);
    f32x2 dA = pk_fma_addk(yA, k6v, k15);
    f32x2 dB = pk_fma_addk(yB, k6v, k15);
    float pA = dA.x * dA.y, qB = dB.x * dB.y;
    float rr = __builtin_amdgcn_rcpf(pA * qB);
    float qr = qB * rr, pr = pA * rr;      // 1/pA, 1/qB
    f32x2 iA; iA.x = dA.y * qr; iA.y = dA.x * qr;
    f32x2 iB; iB.x = dB.y * pr; iB.y = dB.x * pr;
    zA = pk_fma_s1(s4A, kDD, pk_mul(nA, iA));
    zB = pk_fma_s1(s4B, kDD, pk_mul(nB, iB));
  };

#pragma unroll 1
  for (int step = 0; step < NSTEP; step++) {
    // halo prefetch (all OLD; shfl unconditional, then select — R4 lesson).
    // top halo (row above lane's row0) = lane-16's row15; ly==0 -> plane edge 0
    float ax0 = __shfl(u[15][0].x, (lane - 16) & 63);
    float ay0 = __shfl(u[15][0].y, (lane - 16) & 63);
    float ax1 = __shfl(u[15][1].x, (lane - 16) & 63);
    float ay1 = __shfl(u[15][1].y, (lane - 16) & 63);
    f32x2 th0, th1;
    th0.x = (ly == 0) ? 0.f : ax0;
    th0.y = (ly == 0) ? 0.f : ay0;
    th1.x = (ly == 0) ? 0.f : ax1;
    th1.y = (ly == 0) ? 0.f : ay1;
    // bottom halo (row below lane's row15) = lane+16's row0; ly==3 -> 0
    float bx0 = __shfl(u[0][0].x, (lane + 16) & 63);
    float by0 = __shfl(u[0][0].y, (lane + 16) & 63);
    float bx1 = __shfl(u[0][1].x, (lane + 16) & 63);
    float by1 = __shfl(u[0][1].y, (lane + 16) & 63);
    f32x2 bh0, bh1;
    bh0.x = (ly == 3) ? 0.f : bx0;
    bh0.y = (ly == 3) ? 0.f : by0;
    bh1.x = (ly == 3) ? 0.f : bx1;
    bh1.y = (ly == 3) ? 0.f : by1;

    // rows 0..15 in order, in place, rolling prev; side halos JIT via DPP
    f32x2 prev0 = th0, prev1 = th1;
#pragma unroll
    for (int r = 0; r < 16; r++) {
      f32x2 sv0 = u[r][0], sv1 = u[r][1];
      float lfv = dpp_from_left(sv1.y);    // zero at lx==0 by bound_ctrl
      float rtv = dpp_from_right(sv0.x);   // zero at lx==15
      f32x2 dn0 = (r < 15) ? u[r + 1][0] : bh0;
      f32x2 dn1 = (r < 15) ? u[r + 1][1] : bh1;
      f32x2 hs0, hs1;
      hs0.x = lfv + sv0.y;   hs0.y = sv0.x + sv1.x;
      hs1.x = sv0.y + sv1.y; hs1.y = sv1.x + rtv;
      f32x2 s40 = pk_add(pk_add(prev0, dn0), hs0);
      f32x2 s41 = pk_add(pk_add(prev1, dn1), hs1);
      pair2(sv0, sv1, s40, s41, u[r][0], u[r][1]);
      prev0 = sv0; prev1 = sv1;
    }
  }

  // spatial mean: pure wave reduce (no LDS)
  float s = 0.f;
#pragma unroll
  for (int r = 0; r < 16; r++)
#pragma unroll
    for (int q = 0; q < 2; q++) s += u[r][q].x + u[r][q].y;
#pragma unroll
  for (int off = 32; off > 0; off >>= 1) s += __shfl_xor(s, off);
  if (lane == 0) out[plane] = s * (1.f / (HW * HW));
}

// ---------------------------------------------------------------------------
extern "C" void kernel_launch(void* const* d_in, const int* in_sizes, int n_in,
                              void* d_out, int out_size, void* d_ws, size_t ws_size,
                              hipStream_t stream) {
  const float* x    = (const float*)d_in[0];
  const float* W    = (const float*)d_in[1];
  const float* bias = (const float*)d_in[2];
  const float* dc   = (const float*)d_in[3];
  float* out  = (float*)d_out;
  float* proj = (float*)d_ws;   // BATCH*DIM*SEQ*4 = 64 MB

  dim3 g1(DIM / 128, SEQ / 128, BATCH);
  gemm_proj_mfma<<<g1, 256, 0, stream>>>(x, W, bias, proj);

  evolve_kernel<<<(BATCH * DIM) / 4, 256, 0, stream>>>(proj, dc, out);
}